// Round 9
// baseline (180.494 us; speedup 1.0000x reference)
//
#include <hip/hip_runtime.h>

// Problem constants (B=4, S=2048, D=1024, O=1024, C=8)
#define TOK   8192
#define DIM   1024
#define OUTD  1024
#define NCAT  8
#define BM    128
#define BN    128
#define BK    32
#define NKT   (DIM / BK)          // 32 K-tiles
#define MAX_MT 71                 // sum ceil(n_c/128) <= 8192/128 + 7 = 71
#define MPMAX (MAX_MT * BM)       // 9088 padded rows

typedef __attribute__((ext_vector_type(8))) __bf16 bf16x8;
typedef __attribute__((ext_vector_type(4))) float  f32x4;

#define GLP(p)  (const __attribute__((address_space(1))) unsigned int*)(p)
#define LDSP(p) (__attribute__((address_space(3))) unsigned int*)(p)

__device__ __forceinline__ unsigned short f2bf(float f) {
  unsigned u = __float_as_uint(f);
  u += 0x7fffu + ((u >> 16) & 1u);      // RNE
  return (unsigned short)(u >> 16);
}

// ---------------- K1: fused {W transpose+convert} + {token bucketing} -------
// blocks 0..2047: wt[c][o][d] bf16 from w[c][d][o] fp32 (64x64 tiles)
// block 2048:     ballot-based deterministic bucketing (4 waves x 2048 tokens)
__global__ __launch_bounds__(256) void k_prep(const float* __restrict__ w,
    const int* __restrict__ cid, unsigned short* __restrict__ wt,
    int* __restrict__ row_token, int* __restrict__ tile_c, int* __restrict__ tile_m) {
  int tid = threadIdx.x;
  if (blockIdx.x < 2048) {
    int b = blockIdx.x;
    int ot = b & 15, dt = (b >> 4) & 15, c = b >> 8;
    __shared__ unsigned short t[64][72];              // +8: rows stay 16B-aligned
    int i  = tid >> 2;
    int jg = tid & 3;
    const float* src = w + ((size_t)c << 20) + (size_t)(dt * 64 + i) * 1024 + ot * 64 + jg * 16;
    #pragma unroll
    for (int q = 0; q < 4; ++q) {
      float4 v = *(const float4*)(src + q * 4);
      t[jg * 16 + q * 4 + 0][i] = f2bf(v.x);
      t[jg * 16 + q * 4 + 1][i] = f2bf(v.y);
      t[jg * 16 + q * 4 + 2][i] = f2bf(v.z);
      t[jg * 16 + q * 4 + 3][i] = f2bf(v.w);
    }
    __syncthreads();
    unsigned short* dst = wt + ((size_t)c << 20) + (size_t)(ot * 64 + i) * 1024 + dt * 64 + jg * 16;
    uint4 a = *(const uint4*)&t[i][jg * 16];
    uint4 bq = *(const uint4*)&t[i][jg * 16 + 8];
    *(uint4*)dst = a;
    *(uint4*)(dst + 8) = bq;
    return;
  }

  // ---- build block: 4 waves x 2048 tokens each (proven) ----
  __shared__ int wcnt[4][NCAT];
  __shared__ int wbase[4][NCAT];
  __shared__ int gbase[NCAT];
  int lane = tid & 63, wave = tid >> 6;
  int base = wave * 2048;

  int cs[32];
  #pragma unroll
  for (int it = 0; it < 32; ++it) cs[it] = cid[base + it * 64 + lane];
  int cnt_loc[NCAT];
  #pragma unroll
  for (int c = 0; c < NCAT; ++c) cnt_loc[c] = 0;
  #pragma unroll
  for (int it = 0; it < 32; ++it)
    #pragma unroll
    for (int c = 0; c < NCAT; ++c)
      cnt_loc[c] += __popcll(__ballot(cs[it] == c));
  if (lane == 0) {
    #pragma unroll
    for (int c = 0; c < NCAT; ++c) wcnt[wave][c] = cnt_loc[c];
  }
  __syncthreads();

  if (tid == 0) {
    int pr = 0, mt = 0;
    for (int c = 0; c < NCAT; ++c) {
      int tot = 0;
      for (int wv = 0; wv < 4; ++wv) { wbase[wv][c] = tot; tot += wcnt[wv][c]; }
      gbase[c] = pr;
      int nt = (tot + BM - 1) / BM;
      for (int i = 0; i < nt; ++i) { tile_c[mt] = c; tile_m[mt] = pr + i * BM; ++mt; }
      pr += nt * BM;
    }
    for (; mt < MAX_MT; ++mt) { tile_c[mt] = -1; tile_m[mt] = 0; }
  }
  __syncthreads();
  for (int r = tid; r < MPMAX; r += 256) row_token[r] = -1;
  __syncthreads();

  int run[NCAT];
  #pragma unroll
  for (int c = 0; c < NCAT; ++c) run[c] = gbase[c] + wbase[wave][c];
  unsigned long long lt = (lane == 63) ? ~0ull >> 1 : ((1ull << lane) - 1);
  #pragma unroll
  for (int it = 0; it < 32; ++it) {
    int c = cs[it];
    int pos = 0;
    #pragma unroll
    for (int cat = 0; cat < NCAT; ++cat) {
      unsigned long long m = __ballot(cs[it] == cat);
      if (cat == c) pos = run[cat] + __popcll(m & lt);
      run[cat] += __popcll(m);
    }
    row_token[pos] = base + it * 64 + lane;
  }
}

// ---------------- K2: grouped GEMM, fused x gather+convert ------------------
// 128x128x32, 4 waves (2x2), 3-buf LDS. B: global_load_lds (pre-swizzled src),
// A: reg-staged fp32 gather via row_token -> cvt bf16 -> swizzled ds_write.
// Strict 2-deep counted pipeline: 6 vmem issued/iter, vmcnt(6) waits only on
// the PREVIOUS iter's 6 (issue-to-wait = one full K-step). ONE barrier/iter.
__global__ __launch_bounds__(256) void k_gemm(const float* __restrict__ x,
    const unsigned short* __restrict__ wt, const float* __restrict__ bias,
    const int* __restrict__ row_token, const int* __restrict__ tile_c,
    const int* __restrict__ tile_m, float* __restrict__ out) {
  // bijective XCD-chunked remap: grid 568 = 8 XCDs * 71, m-major chunks; the
  // 8 n-blocks of an m-tile co-resident on one XCD -> x rows L2-broadcast.
  int wg  = blockIdx.x;
  int lin = (wg & 7) * MAX_MT + (wg >> 3);
  int mt  = lin >> 3;
  int nt  = lin & 7;
  int c = tile_c[mt];
  if (c < 0) return;
  int m0 = tile_m[mt];
  int n0 = nt * BN;

  __shared__ unsigned short As[3][BM][BK];   // 3 x 8 KB
  __shared__ unsigned short Bs[3][BM][BK];   // 3 x 8 KB

  int tid  = threadIdx.x;
  int lane = tid & 63;
  int wr = (tid >> 6) >> 1, wc = (tid >> 6) & 1;   // 2x2 waves, 64x64 each

  f32x4 acc[4][4];
  #pragma unroll
  for (int m = 0; m < 4; ++m)
    #pragma unroll
    for (int n = 0; n < 4; ++n) acc[m][n] = (f32x4){0.f, 0.f, 0.f, 0.f};

  // ---- A reg-stage setup: one row-half (16 k) per thread ----
  int ra = tid >> 1;                        // 0..127
  int kh = (tid & 1) << 4;                  // 0 or 16 (elements)
  int tokA = row_token[m0 + ra];
  const float* xs = x + (size_t)(tokA < 0 ? 0 : tokA) * DIM + kh;
  int aw = (ra >> 1) & 3;                   // swizzle term for row ra
  int g0 = (tid & 1) << 1;                  // logical granule base (16B units)
  int a0 = ((g0 ^ aw) << 3);                // phys element offsets
  int a1 = (((g0 + 1) ^ aw) << 3);

  // ---- B staging: global_load_lds, linear dest + pre-swizzled source ----
  int srow = tid >> 2;
  int sdst = (tid & 3) << 3;
  int gsrc = (((tid & 3) ^ ((tid >> 3) & 3)) << 3);
  const unsigned short* Bg = wt + ((size_t)c << 20) + (size_t)n0 * DIM;

  auto STAGE_B = [&](int b, int kt) {
    __builtin_amdgcn_global_load_lds(GLP(Bg + (size_t)srow * DIM + kt + gsrc),
                                     LDSP(&Bs[b][srow][sdst]), 16, 0, 0);
    __builtin_amdgcn_global_load_lds(GLP(Bg + (size_t)(srow + 64) * DIM + kt + gsrc),
                                     LDSP(&Bs[b][srow + 64][sdst]), 16, 0, 0);
  };

  float4 sA0[4], sA1[4];                    // two named in-flight A sets (rule 20)
  auto AISSUE = [&](float4 (&s)[4], int t) {
    const float* p = xs + t * BK;
    #pragma unroll
    for (int q = 0; q < 4; ++q) s[q] = *(const float4*)(p + 4 * q);
  };
  auto AWRITE = [&](float4 (&s)[4], int b) {
    bf16x8 p0, p1;
    p0[0] = (__bf16)s[0].x; p0[1] = (__bf16)s[0].y; p0[2] = (__bf16)s[0].z; p0[3] = (__bf16)s[0].w;
    p0[4] = (__bf16)s[1].x; p0[5] = (__bf16)s[1].y; p0[6] = (__bf16)s[1].z; p0[7] = (__bf16)s[1].w;
    p1[0] = (__bf16)s[2].x; p1[1] = (__bf16)s[2].y; p1[2] = (__bf16)s[2].z; p1[3] = (__bf16)s[2].w;
    p1[4] = (__bf16)s[3].x; p1[5] = (__bf16)s[3].y; p1[6] = (__bf16)s[3].z; p1[7] = (__bf16)s[3].w;
    if (tokA < 0) { p0 = (bf16x8){}; p1 = (bf16x8){}; }
    *(bf16x8*)&As[b][ra][a0] = p0;
    *(bf16x8*)&As[b][ra][a1] = p1;
  };

  // per-lane swizzled read granule: phys = logical ^ ((row>>1)&3); row ==
  // base16 + (lane&15) -> XOR term constant per lane.
  int rcol = (((lane >> 4) ^ (((lane & 15) >> 1) & 3)) << 3);
  int arow = wr * 64 + (lane & 15);
  int brow = wc * 64 + (lane & 15);

  // ---- prologue: tiles 0 and 1 in flight ----
  STAGE_B(0, 0);      AISSUE(sA0, 0);       // 6 vmem
  STAGE_B(1, BK);     AISSUE(sA1, 1);       // 12 vmem
  asm volatile("s_waitcnt vmcnt(6)" ::: "memory");   // tile 0's {B,A} done
  AWRITE(sA0, 0);
  asm volatile("s_waitcnt lgkmcnt(0)" ::: "memory");
  __builtin_amdgcn_s_barrier();             // tile 0 resident

  // ---- main loop: iter t computes tile t; sI gets tile t+2, sW holds t+1 ----
  auto BODY = [&](int t, float4 (&sI)[4], float4 (&sW)[4]) {
    bool pre2 = (t + 2 < NKT);
    bool pre1 = (t + 1 < NKT);
    if (pre2) { STAGE_B((t + 2) % 3, (t + 2) * BK); AISSUE(sI, t + 2); }

    int b = t % 3;
    bf16x8 af[4], bf[4];
    #pragma unroll
    for (int m = 0; m < 4; ++m)
      af[m] = *(const bf16x8*)&As[b][arow + m * 16][rcol];
    #pragma unroll
    for (int n = 0; n < 4; ++n)
      bf[n] = *(const bf16x8*)&Bs[b][brow + n * 16][rcol];
    #pragma unroll
    for (int m = 0; m < 4; ++m)
      #pragma unroll
      for (int n = 0; n < 4; ++n)
        acc[m][n] = __builtin_amdgcn_mfma_f32_16x16x32_bf16(af[m], bf[n], acc[m][n], 0, 0, 0);

    if (pre1) {
      if (pre2) asm volatile("s_waitcnt vmcnt(6)" ::: "memory");  // t+1 done
      else      asm volatile("s_waitcnt vmcnt(0)" ::: "memory");
      AWRITE(sW, (t + 1) % 3);
      asm volatile("s_waitcnt lgkmcnt(0)" ::: "memory");          // writes visible
      __builtin_amdgcn_s_barrier();                               // tile t+1 ready
    }
  };
  for (int t2 = 0; t2 < NKT; t2 += 2) {     // NKT even: fixed set parity
    BODY(t2,     sA0, sA1);
    BODY(t2 + 1, sA1, sA0);
  }

  // ---- epilogue: bias + scatter C ----
  int col = lane & 15;
  int rq  = (lane >> 4) << 2;
  float bv[4];
  #pragma unroll
  for (int n = 0; n < 4; ++n) bv[n] = bias[c * OUTD + n0 + wc * 64 + n * 16 + col];
  #pragma unroll
  for (int m = 0; m < 4; ++m) {
    #pragma unroll
    for (int r = 0; r < 4; ++r) {
      int prow = m0 + wr * 64 + m * 16 + rq + r;
      int tok = row_token[prow];
      if (tok < 0) continue;
      float* orow = out + (size_t)tok * OUTD + n0 + wc * 64 + col;
      #pragma unroll
      for (int n = 0; n < 4; ++n) orow[n * 16] = acc[m][n][r] + bv[n];
    }
  }
}

// ---------------- launcher -------------------------------------------------
extern "C" void kernel_launch(void* const* d_in, const int* in_sizes, int n_in,
                              void* d_out, int out_size, void* d_ws, size_t ws_size,
                              hipStream_t stream) {
  const float* x    = (const float*)d_in[0];
  const int*   cid  = (const int*)d_in[1];
  const float* w    = (const float*)d_in[2];
  const float* bias = (const float*)d_in[3];
  float* out = (float*)d_out;

  char* ws = (char*)d_ws;
  constexpr size_t WT_BYTES = (size_t)NCAT * DIM * OUTD * 2;    // 16,777,216
  constexpr size_t RT_BYTES = (size_t)MPMAX * 4;                // 36,352
  unsigned short* wtb = (unsigned short*)ws;
  int* row_token = (int*)(ws + WT_BYTES);
  int* tile_c    = (int*)(ws + WT_BYTES + RT_BYTES);
  int* tile_m    = tile_c + MAX_MT;

  // W transpose+convert (2048 blocks) + token bucketing (block 2048), one dispatch
  k_prep<<<2049, 256, 0, stream>>>(w, cid, wtb, row_token, tile_c, tile_m);
  // grouped GEMM with fused x gather+convert
  k_gemm<<<8 * MAX_MT, 256, 0, stream>>>(x, wtb, bias, row_token, tile_c, tile_m, out);
}

// Round 10
// 156.903 us; speedup vs baseline: 1.1504x; 1.1504x over previous
//
#include <hip/hip_runtime.h>

// Problem constants (B=4, S=2048, D=1024, O=1024, C=8)
#define TOK   8192
#define DIM   1024
#define OUTD  1024
#define NCAT  8
#define BM    128
#define BN    128
#define BK    32
#define NKT   (DIM / BK)          // 32 K-tiles
#define MAX_MT 71                 // sum ceil(n_c/128) <= 8192/128 + 7 = 71
#define MPMAX (MAX_MT * BM)       // 9088 padded rows (row_token sizing)

typedef __attribute__((ext_vector_type(8))) __bf16 bf16x8;
typedef __attribute__((ext_vector_type(4))) float  f32x4;

#define GLP(p)  (const __attribute__((address_space(1))) unsigned int*)(p)
#define LDSP(p) (__attribute__((address_space(3))) unsigned int*)(p)

__device__ __forceinline__ unsigned short f2bf(float f) {
  unsigned u = __float_as_uint(f);
  u += 0x7fffu + ((u >> 16) & 1u);      // RNE
  return (unsigned short)(u >> 16);
}

// ---------------- K1: fused {W transpose+cvt} + {x cvt} + {bucketing} -------
// blocks [0,2048):        wt[c][o][d] bf16 from w[c][d][o] fp32 (64x64 tiles)
// blocks [2048, 6144):    xb[t][d] bf16 = x[t][d] fp32 (pure streaming copy)
// block  6144:            ballot-based deterministic bucketing (4 waves)
__global__ __launch_bounds__(256) void k_prep(const float* __restrict__ w,
    const float* __restrict__ x, const int* __restrict__ cid,
    unsigned short* __restrict__ wt, unsigned short* __restrict__ xb,
    int* __restrict__ row_token, int* __restrict__ tile_c, int* __restrict__ tile_m) {
  int tid = threadIdx.x;
  if (blockIdx.x < 2048) {
    int b = blockIdx.x;
    int ot = b & 15, dt = (b >> 4) & 15, c = b >> 8;
    __shared__ unsigned short t[64][72];              // +8: rows stay 16B-aligned
    int i  = tid >> 2;
    int jg = tid & 3;
    const float* src = w + ((size_t)c << 20) + (size_t)(dt * 64 + i) * 1024 + ot * 64 + jg * 16;
    #pragma unroll
    for (int q = 0; q < 4; ++q) {
      float4 v = *(const float4*)(src + q * 4);
      t[jg * 16 + q * 4 + 0][i] = f2bf(v.x);
      t[jg * 16 + q * 4 + 1][i] = f2bf(v.y);
      t[jg * 16 + q * 4 + 2][i] = f2bf(v.z);
      t[jg * 16 + q * 4 + 3][i] = f2bf(v.w);
    }
    __syncthreads();
    unsigned short* dst = wt + ((size_t)c << 20) + (size_t)(ot * 64 + i) * 1024 + dt * 64 + jg * 16;
    uint4 a = *(const uint4*)&t[i][jg * 16];
    uint4 bq = *(const uint4*)&t[i][jg * 16 + 8];
    *(uint4*)dst = a;
    *(uint4*)(dst + 8) = bq;
    return;
  }
  if (blockIdx.x < 6144) {
    // x fp32 -> bf16, token order, flat: 8M elements / 8 per thread
    size_t idx = ((size_t)(blockIdx.x - 2048) * 256 + tid) * 8;
    const float4* s = (const float4*)(x + idx);
    float4 a = s[0], b = s[1];
    union { unsigned short u[8]; uint4 v; } o;
    o.u[0] = f2bf(a.x); o.u[1] = f2bf(a.y); o.u[2] = f2bf(a.z); o.u[3] = f2bf(a.w);
    o.u[4] = f2bf(b.x); o.u[5] = f2bf(b.y); o.u[6] = f2bf(b.z); o.u[7] = f2bf(b.w);
    *(uint4*)(xb + idx) = o.v;
    return;
  }

  // ---- build block: 4 waves x 2048 tokens each (proven R7/R8) ----
  __shared__ int wcnt[4][NCAT];
  __shared__ int wbase[4][NCAT];
  __shared__ int gbase[NCAT];
  int lane = tid & 63, wave = tid >> 6;
  int base = wave * 2048;

  int cs[32];
  #pragma unroll
  for (int it = 0; it < 32; ++it) cs[it] = cid[base + it * 64 + lane];
  int cnt_loc[NCAT];
  #pragma unroll
  for (int c = 0; c < NCAT; ++c) cnt_loc[c] = 0;
  #pragma unroll
  for (int it = 0; it < 32; ++it)
    #pragma unroll
    for (int c = 0; c < NCAT; ++c)
      cnt_loc[c] += __popcll(__ballot(cs[it] == c));
  if (lane == 0) {
    #pragma unroll
    for (int c = 0; c < NCAT; ++c) wcnt[wave][c] = cnt_loc[c];
  }
  __syncthreads();

  if (tid == 0) {
    int pr = 0, mt = 0;
    for (int c = 0; c < NCAT; ++c) {
      int tot = 0;
      for (int wv = 0; wv < 4; ++wv) { wbase[wv][c] = tot; tot += wcnt[wv][c]; }
      gbase[c] = pr;
      int nt = (tot + BM - 1) / BM;
      for (int i = 0; i < nt; ++i) { tile_c[mt] = c; tile_m[mt] = pr + i * BM; ++mt; }
      pr += nt * BM;
    }
    for (; mt < MAX_MT; ++mt) { tile_c[mt] = -1; tile_m[mt] = 0; }
  }
  __syncthreads();
  for (int r = tid; r < MPMAX; r += 256) row_token[r] = -1;
  __syncthreads();

  int run[NCAT];
  #pragma unroll
  for (int c = 0; c < NCAT; ++c) run[c] = gbase[c] + wbase[wave][c];
  unsigned long long lt = (lane == 63) ? ~0ull >> 1 : ((1ull << lane) - 1);
  #pragma unroll
  for (int it = 0; it < 32; ++it) {
    int c = cs[it];
    int pos = 0;
    #pragma unroll
    for (int cat = 0; cat < NCAT; ++cat) {
      unsigned long long m = __ballot(cs[it] == cat);
      if (cat == c) pos = run[cat] + __popcll(m & lt);
      run[cat] += __popcll(m);
    }
    row_token[pos] = base + it * 64 + lane;
  }
}

// ---------------- K2: grouped GEMM, indirect-A staging, 1 barrier/K-step ----
// 128x128x32, 4 waves (2x2), 3-buf LDS (48 KB). A staged from token-order xb
// via per-lane indirect global_load_lds source (row_token in the address);
// B from wt. Counted vmcnt(4) (never 0 mid-loop); stage t+2 issued AFTER the
// barrier of iter t -> overwrites buffer (t-1)%3 whose reads every wave has
// consumed before barrier arrival (lgkmcnt(0)+sched_barrier guard, rule 18).
__global__ __launch_bounds__(256) void k_gemm(const unsigned short* __restrict__ xb,
    const unsigned short* __restrict__ wt, const float* __restrict__ bias,
    const int* __restrict__ row_token, const int* __restrict__ tile_c,
    const int* __restrict__ tile_m, float* __restrict__ out) {
  // bijective XCD-chunked remap: grid 568 = 8 XCDs * 71, m-major chunks; the
  // 8 n-blocks of an m-tile co-resident on one XCD -> A rows L2-broadcast.
  int wg  = blockIdx.x;
  int lin = (wg & 7) * MAX_MT + (wg >> 3);
  int mt  = lin >> 3;
  int nt  = lin & 7;
  int c = tile_c[mt];
  if (c < 0) return;
  int m0 = tile_m[mt];
  int n0 = nt * BN;

  __shared__ unsigned short As[3][BM][BK];   // 3 x 8 KB
  __shared__ unsigned short Bs[3][BM][BK];   // 3 x 8 KB

  int tid  = threadIdx.x;
  int lane = tid & 63;
  int wr = (tid >> 6) >> 1, wc = (tid >> 6) & 1;   // 2x2 waves, 64x64 each

  f32x4 acc[4][4];
  #pragma unroll
  for (int m = 0; m < 4; ++m)
    #pragma unroll
    for (int n = 0; n < 4; ++n) acc[m][n] = (f32x4){0.f, 0.f, 0.f, 0.f};

  // staging map (R4-proven): row = tid>>2 (0..63, +64), LDS granule = tid&3
  // linear, global source granule XOR-swizzled: phys slot s holds logical
  // s ^ ((row>>1)&3).
  int srow = tid >> 2;
  int sdst = (tid & 3) << 3;
  int gsrc = (((tid & 3) ^ ((tid >> 3) & 3)) << 3);

  // indirect A sources: token-order xb addressed through row_token (per-lane
  // global source of global_load_lds). Pad rows -> token 0 (finite garbage;
  // their C rows are skipped at write).
  int tokA0 = row_token[m0 + srow];
  int tokA1 = row_token[m0 + srow + 64];
  const unsigned short* Ag0 = xb + (size_t)(tokA0 < 0 ? 0 : tokA0) * DIM + gsrc;
  const unsigned short* Ag1 = xb + (size_t)(tokA1 < 0 ? 0 : tokA1) * DIM + gsrc;
  const unsigned short* Bg  = wt + ((size_t)c << 20) + (size_t)n0 * DIM + gsrc;

  auto STAGE = [&](int b, int kt) {
    __builtin_amdgcn_global_load_lds(GLP(Ag0 + kt), LDSP(&As[b][srow][sdst]), 16, 0, 0);
    __builtin_amdgcn_global_load_lds(GLP(Ag1 + kt), LDSP(&As[b][srow + 64][sdst]), 16, 0, 0);
    __builtin_amdgcn_global_load_lds(GLP(Bg + (size_t)srow * DIM + kt), LDSP(&Bs[b][srow][sdst]), 16, 0, 0);
    __builtin_amdgcn_global_load_lds(GLP(Bg + (size_t)(srow + 64) * DIM + kt), LDSP(&Bs[b][srow + 64][sdst]), 16, 0, 0);
  };

  // per-lane swizzled read granule: phys = logical ^ ((row>>1)&3); row =
  // base16 + (lane&15) -> XOR term constant per lane.
  int rcol = (((lane >> 4) ^ (((lane & 15) >> 1) & 3)) << 3);
  int arow = wr * 64 + (lane & 15);
  int brow = wc * 64 + (lane & 15);

  // prologue: 2 tiles in flight
  STAGE(0, 0); STAGE(1, BK);

  for (int t = 0; t < NKT; ++t) {
    // wait tile t resident (stage t+1's 4 loads stay outstanding); drain own
    // ds_reads of iter t-1 (lgkm) so the barrier certifies buffer (t-1)%3 free.
    if (t < NKT - 1) asm volatile("s_waitcnt vmcnt(4) lgkmcnt(0)" ::: "memory");
    else             asm volatile("s_waitcnt vmcnt(0) lgkmcnt(0)" ::: "memory");
    __builtin_amdgcn_sched_barrier(0);
    __builtin_amdgcn_s_barrier();
    if (t + 2 < NKT) STAGE((t + 2) % 3, (t + 2) * BK);   // overwrites (t-1)%3

    int b = t % 3;
    bf16x8 af[4], bf[4];
    #pragma unroll
    for (int m = 0; m < 4; ++m)
      af[m] = *(const bf16x8*)&As[b][arow + m * 16][rcol];
    #pragma unroll
    for (int n = 0; n < 4; ++n)
      bf[n] = *(const bf16x8*)&Bs[b][brow + n * 16][rcol];
    #pragma unroll
    for (int m = 0; m < 4; ++m)
      #pragma unroll
      for (int n = 0; n < 4; ++n)
        acc[m][n] = __builtin_amdgcn_mfma_f32_16x16x32_bf16(af[m], bf[n], acc[m][n], 0, 0, 0);
  }

  // ---- epilogue: bias + scatter C ----
  int col = lane & 15;
  int rq  = (lane >> 4) << 2;
  float bv[4];
  #pragma unroll
  for (int n = 0; n < 4; ++n) bv[n] = bias[c * OUTD + n0 + wc * 64 + n * 16 + col];
  #pragma unroll
  for (int m = 0; m < 4; ++m) {
    #pragma unroll
    for (int r = 0; r < 4; ++r) {
      int prow = m0 + wr * 64 + m * 16 + rq + r;
      int tok = row_token[prow];
      if (tok < 0) continue;
      float* orow = out + (size_t)tok * OUTD + n0 + wc * 64 + col;
      #pragma unroll
      for (int n = 0; n < 4; ++n) orow[n * 16] = acc[m][n][r] + bv[n];
    }
  }
}

// ---------------- launcher -------------------------------------------------
extern "C" void kernel_launch(void* const* d_in, const int* in_sizes, int n_in,
                              void* d_out, int out_size, void* d_ws, size_t ws_size,
                              hipStream_t stream) {
  const float* x    = (const float*)d_in[0];
  const int*   cid  = (const int*)d_in[1];
  const float* w    = (const float*)d_in[2];
  const float* bias = (const float*)d_in[3];
  float* out = (float*)d_out;

  char* ws = (char*)d_ws;
  constexpr size_t XB_BYTES = (size_t)TOK * DIM * 2;            // 16,777,216
  constexpr size_t WT_BYTES = (size_t)NCAT * DIM * OUTD * 2;    // 16,777,216
  constexpr size_t RT_BYTES = (size_t)MPMAX * 4;                // 36,352
  unsigned short* xbb = (unsigned short*)ws;
  unsigned short* wtb = (unsigned short*)(ws + XB_BYTES);
  int* row_token = (int*)(ws + XB_BYTES + WT_BYTES);
  int* tile_c    = (int*)(ws + XB_BYTES + WT_BYTES + RT_BYTES);
  int* tile_m    = tile_c + MAX_MT;

  // one prep dispatch: W transpose+cvt (2048) + x cvt (4096) + bucketing (1)
  k_prep<<<6145, 256, 0, stream>>>(w, x, cid, wtb, xbb, row_token, tile_c, tile_m);
  // grouped GEMM with indirect-A staging
  k_gemm<<<8 * MAX_MT, 256, 0, stream>>>(xbb, wtb, bias, row_token, tile_c, tile_m, out);
}